// Round 8
// baseline (795.718 us; speedup 1.0000x reference)
//
#include <hip/hip_runtime.h>
#include <hip/hip_bf16.h>

#define HIDDEN 128
#define DEPTH 4
#define INTER 512
#define NSTATE 16
#define DT_RANK 8
#define EPS_RMS 1e-5f
#define MTOK 512            // B*T
#define KIN 150528
#define NBLK 256            // tail persistent-kernel grid (1 block/CU)
#define BARSTRIDE 1024      // u32 per barrier region

typedef __attribute__((ext_vector_type(8))) short bf16x8;
typedef __attribute__((ext_vector_type(4))) float f32x4;

__device__ __forceinline__ unsigned short f2bf(float f) {
  unsigned int u = __builtin_bit_cast(unsigned int, f);
  u += 0x7fffu + ((u >> 16) & 1u);
  return (unsigned short)(u >> 16);
}
__device__ __forceinline__ float silu_f(float x) {
  return x / (1.0f + __expf(-x));
}
__device__ __forceinline__ float f4sum(f32x4 v) {
  return (v.x + v.y) + (v.z + v.w);
}

// ---------------------------------------------------------------------------
// One-shot grid barrier: two-level arrival (8 groups x 32 blocks), RELAXED
// spin + single ACQUIRE at exit (R6-proven orders; R7's grouped arrival).
// region: root = region[0]; group g counter = region[32 + 32*g].
// ---------------------------------------------------------------------------
__device__ __forceinline__ void gbar(unsigned* region)
{
  __syncthreads();
  if (threadIdx.x == 0) {
    const unsigned g = (unsigned)blockIdx.x >> 5;       // 0..7
    const unsigned old = __hip_atomic_fetch_add(&region[32 + 32 * g], 1u,
                                                __ATOMIC_RELEASE,
                                                __HIP_MEMORY_SCOPE_AGENT);
    if (old == 31u)
      (void)__hip_atomic_fetch_add(&region[0], 1u, __ATOMIC_RELEASE,
                                   __HIP_MEMORY_SCOPE_AGENT);
    while (__hip_atomic_load(&region[0], __ATOMIC_RELAXED,
                             __HIP_MEMORY_SCOPE_AGENT) < 8u)
      __builtin_amdgcn_s_sleep(8);
    (void)__hip_atomic_load(&region[0], __ATOMIC_ACQUIRE,
                            __HIP_MEMORY_SCOPE_AGENT);
  }
  __syncthreads();
}

// ---------------------------------------------------------------------------
// zero_part: 4 MB partial buffer zero + 32 KB barrier-region zero.
// ---------------------------------------------------------------------------
__global__ __launch_bounds__(256) void zero_part(float* __restrict__ p,
                                                 unsigned* __restrict__ bar)
{
  const size_t i = (size_t)blockIdx.x * 256 + threadIdx.x;
  ((float4*)p)[i] = (float4){0.f, 0.f, 0.f, 0.f};
  if (blockIdx.x < 8) {
    uint4* b4 = (uint4*)bar;
    b4[(size_t)blockIdx.x * 256 + threadIdx.x] = (uint4){0u, 0u, 0u, 0u};
  }
}

// ---------------------------------------------------------------------------
// Projection GEMM v3 (unchanged, ~85-137 us): zero-duplication tiling.
// ---------------------------------------------------------------------------
__global__ __launch_bounds__(512) void proj_gemm(
    const float* __restrict__ x, const float* __restrict__ w,
    float* __restrict__ partial)
{
  const int bid = blockIdx.x;          // 0..255
  const int mb = (bid >> 3) & 3;       // 0..3  (M-tile of 128 rows)
  const int kb = (bid & 7) + (bid >> 5) * 8;   // 0..63 (XCD-clustered)
  const int nchunk = 18 + (kb < 24 ? 1 : 0);
  const int c0 = kb * 18 + (kb < 24 ? kb : 24);

  __shared__ char sm[256 * 256];       // 256 rows (x:0-127, w:128-255) x 256 B

  const int tid = threadIdx.x;
  const int lane = tid & 63;
  const int wv = tid >> 6;             // 0..7
  const int wm2 = wv >> 2;             // 0..1  M-half (64 rows)
  const int wn4 = wv & 3;              // 0..3  N-quarter (32 cols)
  const int fr = lane & 15;
  const int kq = lane >> 4;            // 0..3
  const int l31 = lane & 31;
  const int rpar = lane >> 5;          // 0/1

  const float* gptr = (wv < 4)
      ? (x + (size_t)(mb * 128 + wv * 32 + rpar) * KIN + l31 * 4)
      : (w + (size_t)((wv - 4) * 32 + rpar) * KIN + l31 * 4);

  f32x4 acc[4][2];
  #pragma unroll
  for (int mi = 0; mi < 4; ++mi) {
    acc[mi][0] = (f32x4){0.f, 0.f, 0.f, 0.f};
    acc[mi][1] = (f32x4){0.f, 0.f, 0.f, 0.f};
  }

  float4 rv[16];
  {
    const float* base = gptr + (size_t)c0 * 128;
    #pragma unroll
    for (int j = 0; j < 16; ++j)
      rv[j] = *(const float4*)(base + (size_t)(j * 2) * KIN);
  }

  for (int cc = 0; cc < nchunk; ++cc) {
    #pragma unroll
    for (int j = 0; j < 16; ++j) {
      const int r = wv * 32 + j * 2 + rpar;
      const int phys = (l31 * 8) ^ ((r & 7) << 4);
      ushort4 bq = {f2bf(rv[j].x), f2bf(rv[j].y), f2bf(rv[j].z), f2bf(rv[j].w)};
      *(ushort4*)(sm + r * 256 + phys) = bq;
    }
    __syncthreads();
    if (cc + 1 < nchunk) {
      const float* base = gptr + (size_t)(c0 + cc + 1) * 128;
      #pragma unroll
      for (int j = 0; j < 16; ++j)
        rv[j] = *(const float4*)(base + (size_t)(j * 2) * KIN);
    }
    #pragma unroll
    for (int ks = 0; ks < 4; ++ks) {
      const int log = ks * 64 + kq * 16;
      bf16x8 a[4];
      #pragma unroll
      for (int mi = 0; mi < 4; ++mi) {
        const int row = wm2 * 64 + mi * 16 + fr;
        a[mi] = *(const bf16x8*)(sm + row * 256 + (log ^ ((row & 7) << 4)));
      }
      #pragma unroll
      for (int ni = 0; ni < 2; ++ni) {
        const int row = 128 + wn4 * 32 + ni * 16 + fr;
        const bf16x8 b = *(const bf16x8*)(sm + row * 256 + (log ^ ((row & 7) << 4)));
        #pragma unroll
        for (int mi = 0; mi < 4; ++mi)
          acc[mi][ni] = __builtin_amdgcn_mfma_f32_16x16x32_bf16(a[mi], b, acc[mi][ni], 0, 0, 0);
      }
    }
    __syncthreads();
  }
  float* hp = partial + (size_t)(kb & 15) * (MTOK * HIDDEN);
  #pragma unroll
  for (int mi = 0; mi < 4; ++mi)
    #pragma unroll
    for (int ni = 0; ni < 2; ++ni)
      #pragma unroll
      for (int r = 0; r < 4; ++r) {
        const int row = mb * 128 + wm2 * 64 + mi * 16 + kq * 4 + r;
        const int col = wn4 * 32 + ni * 16 + fr;
        atomicAdd(hp + (size_t)row * HIDDEN + col, acc[mi][ni][r]);
      }
}

// ---------------------------------------------------------------------------
// tail_pers v3: 9 phases, 8 barriers. FA+CONV fused via 3-token redundant
// halo compute (hs never leaves LDS). h and gate double-buffered to remove
// the same-phase cross-block read/write race.
// LDS map (floats): [0,2560) y2/hs_loc union | [2560,3200) hrow / u_loc lo |
// [3200,3840) hn / u_loc hi+si. Sequencing makes each overlap safe.
// ---------------------------------------------------------------------------
struct TailArgs {
  const float* part; const float* pb;
  float* hA; float* hB; float* gA; float* gB;
  float* uT; float* dtT; float* Bm; float* Cm; float* y;
  float* out;
  const float* ipw; const float* cw; const float* cb;
  const float* xpw; const float* dtw; const float* dtb;
  const float* Alog; const float* Dssm; const float* opw;
  const float* nw; const float* nwf;
  unsigned* bar;
};

// in_proj (5-token hs half + 2-token gate half, weight-stationary) -> conv
// -> x_proj -> B/C/dt.  lw = layer index for these weights.
// Requires hn = sm+3200 valid; uses hs_loc = sm, u_loc = sm+2560, si = sm+3584.
__device__ __forceinline__ void inproj_conv_xp(
    const TailArgs& A, int lw, float* sm, int b, int tb0, int m0,
    float* gout, int tid)
{
  float* hs_loc = sm;            // [5][512]
  float* hn     = sm + 3200;     // [5][128]
  float* u_loc  = sm + 2560;     // [2][512]
  float* si     = sm + 3584;     // [2][40]
  const float* ipw = A.ipw + (size_t)lw * 1024 * 128;
  {  // hs half: thread owns weight row e=tid, dots 5 tokens
    const f32x4* wp = (const f32x4*)(ipw + (size_t)tid * 128);
    const f32x4* h0 = (const f32x4*)(hn);
    const f32x4* h1 = (const f32x4*)(hn + 128);
    const f32x4* h2 = (const f32x4*)(hn + 256);
    const f32x4* h3 = (const f32x4*)(hn + 384);
    const f32x4* h4 = (const f32x4*)(hn + 512);
    f32x4 a0 = {0.f,0.f,0.f,0.f}, a1 = a0, a2 = a0, a3 = a0, a4 = a0;
    #pragma unroll
    for (int kk = 0; kk < 32; ++kk) {
      const f32x4 wv4 = wp[kk];
      a0 += h0[kk] * wv4; a1 += h1[kk] * wv4; a2 += h2[kk] * wv4;
      a3 += h3[kk] * wv4; a4 += h4[kk] * wv4;
    }
    hs_loc[tid]          = f4sum(a0);
    hs_loc[512 + tid]    = f4sum(a1);
    hs_loc[1024 + tid]   = f4sum(a2);
    hs_loc[1536 + tid]   = f4sum(a3);
    hs_loc[2048 + tid]   = f4sum(a4);
  }
  {  // gate half: own 2 tokens only
    const f32x4* wp = (const f32x4*)(ipw + (size_t)(512 + tid) * 128);
    const f32x4* h3 = (const f32x4*)(hn + 384);
    const f32x4* h4 = (const f32x4*)(hn + 512);
    f32x4 g3 = {0.f,0.f,0.f,0.f}, g4 = g3;
    #pragma unroll
    for (int kk = 0; kk < 32; ++kk) {
      const f32x4 wv4 = wp[kk];
      g3 += h3[kk] * wv4; g4 += h4[kk] * wv4;
    }
    gout[(size_t)m0 * 512 + tid]       = f4sum(g3);
    gout[(size_t)(m0 + 1) * 512 + tid] = f4sum(g4);
  }
  __syncthreads();
  // conv + silu for own 2 tokens (window rows t..t+3 feed token tb0+t)
  const float* cw = A.cw + (size_t)lw * 2048;
  const float* cb = A.cb + (size_t)lw * 512;
  #pragma unroll
  for (int jj = 0; jj < 2; ++jj) {
    const int o = tid + jj * 512, t = o >> 9, i = o & 511;
    const float4 c4v = *(const float4*)(cw + (size_t)i * 4);
    const float s = cb[i] + c4v.x * hs_loc[t * 512 + i]
                          + c4v.y * hs_loc[(t + 1) * 512 + i]
                          + c4v.z * hs_loc[(t + 2) * 512 + i]
                          + c4v.w * hs_loc[(t + 3) * 512 + i];
    const float uu = silu_f(s);
    u_loc[t * 512 + i] = uu;
    A.uT[((size_t)b * 512 + i) * 256 + tb0 + t] = uu;
  }
  __syncthreads();
  // x_proj
  const float* xpw = A.xpw + (size_t)lw * 40 * 512;
  if (tid < 160) {
    const int pid = tid >> 1, half = tid & 1;
    const int t = pid / 40, e = pid % 40;
    const float4* up = (const float4*)(u_loc + t * 512 + half * 256);
    const float4* wp = (const float4*)(xpw + (size_t)e * 512 + half * 256);
    float b0 = 0.f, b1 = 0.f, b2 = 0.f, b3 = 0.f;
    #pragma unroll 8
    for (int kk = 0; kk < 64; ++kk) {
      const float4 uv = up[kk], wv4 = wp[kk];
      b0 += uv.x * wv4.x; b1 += uv.y * wv4.y;
      b2 += uv.z * wv4.z; b3 += uv.w * wv4.w;
    }
    float a = (b0 + b1) + (b2 + b3);
    a += __shfl_xor(a, 1);
    if (half == 0) si[t * 40 + e] = a;
  }
  __syncthreads();
  if (tid < 64) {
    const int t = tid >> 5, q = tid & 31;
    if (q < 16) A.Bm[(size_t)(m0 + t) * 16 + q] = si[t * 40 + 8 + q];
    else        A.Cm[(size_t)(m0 + t) * 16 + (q - 16)] = si[t * 40 + 24 + (q - 16)];
  }
  const float* dtw = A.dtw + (size_t)lw * 512 * 8;
  const float* dtb = A.dtb + (size_t)lw * 512;
  #pragma unroll
  for (int jj = 0; jj < 2; ++jj) {
    const int o = tid + jj * 512;
    const int i = o >> 1, t = o & 1;
    float a0 = dtb[i];
    const float* dr = dtw + (size_t)i * 8;
    #pragma unroll
    for (int r = 0; r < 8; ++r) a0 += si[t * 40 + r] * dr[r];
    const float sp = (a0 > 20.f) ? a0 : log1pf(__expf(a0));
    A.dtT[((size_t)b * 512 + i) * 256 + tb0 + t] = sp;
  }
}

__global__ __launch_bounds__(512) void tail_pers(TailArgs A)
{
  const int blk = blockIdx.x;          // 0..255
  const int tid = threadIdx.x;
  const int m0 = blk * 2;
  const int b = m0 >> 8, tb0 = m0 & 255;
  int bk = 0;

  __shared__ __align__(16) float sm[3840];   // 15 KB
  float* hrow = sm + 2560;                   // [5][128]
  float* hn   = sm + 3200;                   // [5][128]

  // ================= phase A0CONV: h0 window, rms, in_proj0, conv0 =========
  {
    for (int o = tid; o < 640; o += 512) {
      const int j = o >> 7, d = o & 127;
      const int wt = tb0 - 3 + j;
      float hv = 0.f;
      if (wt >= 0) {
        const int gt = b * 256 + wt;
        hv = A.pb[d];
        #pragma unroll
        for (int s = 0; s < 16; ++s)
          hv += A.part[(size_t)s * (MTOK * HIDDEN) + (size_t)gt * 128 + d];
        if (j >= 3) A.hA[(size_t)gt * 128 + d] = hv;
      }
      hrow[j * 128 + d] = hv;
    }
    __syncthreads();
    {
      const int wv = tid >> 6, ln = tid & 63;
      if (wv < 5) {
        const float v0 = hrow[wv * 128 + ln], v1 = hrow[wv * 128 + ln + 64];
        float ss = v0 * v0 + v1 * v1;
        #pragma unroll
        for (int off = 1; off < 64; off <<= 1) ss += __shfl_xor(ss, off);
        const float rr = rsqrtf(ss * (1.0f / 128.0f) + EPS_RMS);
        hn[wv * 128 + ln]      = v0 * rr * A.nw[ln];
        hn[wv * 128 + ln + 64] = v1 * rr * A.nw[ln + 64];
      }
    }
    __syncthreads();
    inproj_conv_xp(A, 0, sm, b, tb0, m0, A.gA, tid);
  }
  gbar(A.bar + (bk++) * BARSTRIDE);

  for (int l = 0; l < DEPTH; ++l) {
    // ================= phase SCAN(l): 4 units/block (R6-proven) ============
    {
      float* dt_l = sm;            // [2][256]
      float* u_l  = sm + 512;      // [2][256]
      float* e_l  = sm + 1024;     // [2][272]
      float* P_l  = sm + 1568;     // [2][272]
      const float* Alg = A.Alog + (size_t)l * INTER * NSTATE;
      const float* Dsp = A.Dssm + (size_t)l * INTER;
      const int sub = tid >> 8;
      const int t2 = tid & 255;
      const int c = t2 >> 4, n = t2 & 15;
      for (int rd = 0; rd < 2; ++rd) {
        const int unit = blk * 4 + sub * 2 + rd;
        const int sb = unit >> 9, si_ = unit & 511;
        dt_l[sub * 256 + t2] = A.dtT[((size_t)sb * 512 + si_) * 256 + t2];
        u_l [sub * 256 + t2] = A.uT [((size_t)sb * 512 + si_) * 256 + t2];
        const float Av = -__expf(Alg[(size_t)si_ * 16 + n]);
        const float Dv = Dsp[si_];
        float Bv[16], Cv[16];
        #pragma unroll
        for (int j = 0; j < 16; ++j) {
          const int t = c * 16 + j;
          Bv[j] = A.Bm[(size_t)sb * 4096 + t * 16 + n];
          Cv[j] = A.Cm[(size_t)sb * 4096 + t * 16 + n];
        }
        __syncthreads();
        float aj[16];
        float s = 0.f, P = 1.f;
        #pragma unroll
        for (int j = 0; j < 16; ++j) {
          const int t = c * 16 + j;
          const float dtv = dt_l[sub * 256 + t];
          const float a = __expf(Av * dtv);
          aj[j] = a;
          s = a * s + dtv * Bv[j] * u_l[sub * 256 + t];
          P *= a;
        }
        e_l[sub * 272 + c * 17 + n] = s;
        P_l[sub * 272 + c * 17 + n] = P;
        __syncthreads();
        float s0 = 0.f;
        for (int cc = 0; cc < c; ++cc)
          s0 = P_l[sub * 272 + cc * 17 + n] * s0 + e_l[sub * 272 + cc * 17 + n];
        s = s0;
        #pragma unroll
        for (int j = 0; j < 16; ++j) {
          const int t = c * 16 + j;
          const float dtv = dt_l[sub * 256 + t];
          s = aj[j] * s + dtv * Bv[j] * u_l[sub * 256 + t];
          float p = s * Cv[j];
          p += __shfl_xor(p, 1); p += __shfl_xor(p, 2);
          p += __shfl_xor(p, 4); p += __shfl_xor(p, 8);
          if (n == 0)
            A.y[((size_t)sb * 256 + t) * 512 + si_] = p + u_l[sub * 256 + t] * Dv;
        }
        __syncthreads();
      }
    }
    gbar(A.bar + (bk++) * BARSTRIDE);

    if (l < 3) {
      // ============== phase FACONV(l): out_proj+res(5tok), rms, in_proj(l+1),
      //                conv(l+1) ==========================================
      const float* hin  = (l & 1) ? A.hB : A.hA;
      float*       hout = (l & 1) ? A.hA : A.hB;
      const float* gin  = (l & 1) ? A.gB : A.gA;
      float*       gout = (l & 1) ? A.gA : A.gB;
      float* y2 = sm;                          // [5][512]
      const float* opw = A.opw + (size_t)l * 128 * 512;
      for (int o = tid; o < 2560; o += 512) {
        const int j = o >> 9, i = o & 511;
        const int wt = tb0 - 3 + j;
        float v = 0.f;
        if (wt >= 0) {
          const int gt = b * 256 + wt;
          v = A.y[(size_t)gt * 512 + i] * silu_f(gin[(size_t)gt * 512 + i]);
        }
        y2[j * 512 + i] = v;
      }
      __syncthreads();
      {
        const int d = tid >> 2, kq = tid & 3;
        const f32x4* wp = (const f32x4*)(opw + (size_t)d * 512 + kq * 128);
        const f32x4* y0 = (const f32x4*)(y2 + kq * 128);
        const f32x4* y1 = (const f32x4*)(y2 + 512 + kq * 128);
        const f32x4* yy2 = (const f32x4*)(y2 + 1024 + kq * 128);
        const f32x4* y3 = (const f32x4*)(y2 + 1536 + kq * 128);
        const f32x4* y4 = (const f32x4*)(y2 + 2048 + kq * 128);
        f32x4 a0 = {0.f,0.f,0.f,0.f}, a1 = a0, a2 = a0, a3 = a0, a4 = a0;
        #pragma unroll
        for (int kk = 0; kk < 32; ++kk) {
          const f32x4 wv4 = wp[kk];
          a0 += y0[kk] * wv4; a1 += y1[kk] * wv4; a2 += yy2[kk] * wv4;
          a3 += y3[kk] * wv4; a4 += y4[kk] * wv4;
        }
        float r[5] = { f4sum(a0), f4sum(a1), f4sum(a2), f4sum(a3), f4sum(a4) };
        #pragma unroll
        for (int j = 0; j < 5; ++j) {
          float a = r[j];
          a += __shfl_xor(a, 1); a += __shfl_xor(a, 2);
          if (kq == 0) {
            const int wt = tb0 - 3 + j;
            if (wt >= 0) {
              const int gt = b * 256 + wt;
              const float hv = hin[(size_t)gt * 128 + d] + a;
              hrow[j * 128 + d] = hv;
              if (j >= 3) hout[(size_t)gt * 128 + d] = hv;
            } else hrow[j * 128 + d] = 0.f;
          }
        }
      }
      __syncthreads();
      {
        const float* nwp = A.nw + (size_t)(l + 1) * 128;
        const int wv = tid >> 6, ln = tid & 63;
        if (wv < 5) {
          const float v0 = hrow[wv * 128 + ln], v1 = hrow[wv * 128 + ln + 64];
          float ss = v0 * v0 + v1 * v1;
          #pragma unroll
          for (int off = 1; off < 64; off <<= 1) ss += __shfl_xor(ss, off);
          const float rr = rsqrtf(ss * (1.0f / 128.0f) + EPS_RMS);
          hn[wv * 128 + ln]      = v0 * rr * nwp[ln];
          hn[wv * 128 + ln + 64] = v1 * rr * nwp[ln + 64];
        }
      }
      __syncthreads();
      inproj_conv_xp(A, l + 1, sm, b, tb0, m0, gout, tid);
      gbar(A.bar + (bk++) * BARSTRIDE);
    } else {
      // ============== phase FAFIN: out_proj(l=3)+res, final rms -> out =====
      float* y2 = sm;                          // [2][512]
      const float* opw = A.opw + (size_t)3 * 128 * 512;
      #pragma unroll
      for (int jj = 0; jj < 2; ++jj) {
        const int o = tid + jj * 512, t = o >> 9, i = o & 511;
        const int gt = m0 + t;
        y2[t * 512 + i] = A.y[(size_t)gt * 512 + i] *
                          silu_f(A.gB[(size_t)gt * 512 + i]);
      }
      __syncthreads();
      {
        const int d = tid >> 2, kq = tid & 3;
        const f32x4* wp = (const f32x4*)(opw + (size_t)d * 512 + kq * 128);
        const f32x4* y0 = (const f32x4*)(y2 + kq * 128);
        const f32x4* y1 = (const f32x4*)(y2 + 512 + kq * 128);
        f32x4 a0 = {0.f,0.f,0.f,0.f}, a1 = a0;
        #pragma unroll
        for (int kk = 0; kk < 32; ++kk) {
          const f32x4 wv4 = wp[kk];
          a0 += y0[kk] * wv4; a1 += y1[kk] * wv4;
        }
        float s0 = f4sum(a0), s1 = f4sum(a1);
        s0 += __shfl_xor(s0, 1); s0 += __shfl_xor(s0, 2);
        s1 += __shfl_xor(s1, 1); s1 += __shfl_xor(s1, 2);
        if (kq == 0) {
          hrow[d]       = A.hB[(size_t)m0 * 128 + d] + s0;
          hrow[128 + d] = A.hB[(size_t)(m0 + 1) * 128 + d] + s1;
        }
      }
      __syncthreads();
      if (tid < 128) {
        const int wv = tid >> 6, ln = tid & 63;
        const float v0 = hrow[wv * 128 + ln], v1 = hrow[wv * 128 + ln + 64];
        float ss = v0 * v0 + v1 * v1;
        #pragma unroll
        for (int off = 1; off < 64; off <<= 1) ss += __shfl_xor(ss, off);
        const float rr = rsqrtf(ss * (1.0f / 128.0f) + EPS_RMS);
        A.out[(size_t)(m0 + wv) * 128 + ln]      = v0 * rr * A.nwf[ln];
        A.out[(size_t)(m0 + wv) * 128 + ln + 64] = v1 * rr * A.nwf[ln + 64];
      }
    }
  }
}

extern "C" void kernel_launch(void* const* d_in, const int* in_sizes, int n_in,
                              void* d_out, int out_size, void* d_ws, size_t ws_size,
                              hipStream_t stream)
{
  (void)in_sizes; (void)n_in; (void)out_size; (void)ws_size;
  const float* x    = (const float*)d_in[0];
  const float* pw   = (const float*)d_in[1];
  const float* pb   = (const float*)d_in[2];
  const float* ipw  = (const float*)d_in[3];
  const float* cw   = (const float*)d_in[4];
  const float* cb   = (const float*)d_in[5];
  const float* xpw  = (const float*)d_in[6];
  const float* dtw  = (const float*)d_in[7];
  const float* dtb  = (const float*)d_in[8];
  const float* Alog = (const float*)d_in[9];
  const float* Dssm = (const float*)d_in[10];
  const float* opw  = (const float*)d_in[11];
  const float* nw   = (const float*)d_in[12];
  const float* nwf  = (const float*)d_in[13];
  float* out = (float*)d_out;

  float* ws   = (float*)d_ws;                 // ~10 MB scratch
  float* part = ws;                           // 16 * 65536 (atomic-accumulated)
  float* hA   = part + 16 * 65536;            // 65536
  float* hB   = hA + 65536;                   // 65536
  float* gA   = hB + 65536;                   // 262144
  float* gB   = gA + 262144;                  // 262144
  float* uT   = gB + 262144;                  // 262144
  float* dtT  = uT + 262144;                  // 262144
  float* Bm   = dtT + 262144;                 // 8192
  float* Cm   = Bm + 8192;                    // 8192
  float* y    = Cm + 8192;                    // 262144
  unsigned* bar = (unsigned*)(y + 262144);    // 8 * 1024 u32 = 32 KB

  zero_part<<<dim3(1024), 256, 0, stream>>>(part, bar);
  proj_gemm<<<dim3(256), 512, 0, stream>>>(x, pw, part);

  TailArgs ta;
  ta.part = part; ta.pb = pb;
  ta.hA = hA; ta.hB = hB; ta.gA = gA; ta.gB = gB;
  ta.uT = uT; ta.dtT = dtT; ta.Bm = Bm; ta.Cm = Cm; ta.y = y;
  ta.out = out;
  ta.ipw = ipw; ta.cw = cw; ta.cb = cb;
  ta.xpw = xpw; ta.dtw = dtw; ta.dtb = dtb;
  ta.Alog = Alog; ta.Dssm = Dssm; ta.opw = opw;
  ta.nw = nw; ta.nwf = nwf;
  ta.bar = bar;

  tail_pers<<<dim3(NBLK), 512, 0, stream>>>(ta);
}

// Round 9
// 416.439 us; speedup vs baseline: 1.9108x; 1.9108x over previous
//
#include <hip/hip_runtime.h>
#include <hip/hip_bf16.h>

#define HIDDEN 128
#define DEPTH 4
#define INTER 512
#define NSTATE 16
#define DT_RANK 8
#define EPS_RMS 1e-5f
#define MTOK 512            // B*T
#define KIN 150528

typedef __attribute__((ext_vector_type(8))) short bf16x8;
typedef __attribute__((ext_vector_type(4))) float f32x4;

__device__ __forceinline__ unsigned short f2bf(float f) {
  unsigned int u = __builtin_bit_cast(unsigned int, f);
  u += 0x7fffu + ((u >> 16) & 1u);
  return (unsigned short)(u >> 16);
}
__device__ __forceinline__ float silu_f(float x) {
  return x / (1.0f + __expf(-x));
}

// ---------------------------------------------------------------------------
// zero_part: 4 MB partial buffer zero (1024 x 256 x float4).
// ---------------------------------------------------------------------------
__global__ __launch_bounds__(256) void zero_part(float* __restrict__ p)
{
  const size_t i = (size_t)blockIdx.x * 256 + threadIdx.x;
  ((float4*)p)[i] = (float4){0.f, 0.f, 0.f, 0.f};
}

// ---------------------------------------------------------------------------
// Projection GEMM v3 (R3-proven): zero-duplication tiling.
// grid 256 = mb(4) x kb(64); NT=128 (x read once), k-chunk 128 -> 512-B
// bursts; 64 KB LDS bf16, swizzled; atomicAdd into 16 slices.
// ---------------------------------------------------------------------------
__global__ __launch_bounds__(512) void proj_gemm(
    const float* __restrict__ x, const float* __restrict__ w,
    float* __restrict__ partial)
{
  const int bid = blockIdx.x;          // 0..255
  const int mb = (bid >> 3) & 3;       // 0..3  (M-tile of 128 rows)
  const int kb = (bid & 7) + (bid >> 5) * 8;   // 0..63 (XCD-clustered)
  const int nchunk = 18 + (kb < 24 ? 1 : 0);
  const int c0 = kb * 18 + (kb < 24 ? kb : 24);

  __shared__ char sm[256 * 256];       // 256 rows (x:0-127, w:128-255) x 256 B

  const int tid = threadIdx.x;
  const int lane = tid & 63;
  const int wv = tid >> 6;             // 0..7
  const int wm2 = wv >> 2;             // 0..1  M-half (64 rows)
  const int wn4 = wv & 3;              // 0..3  N-quarter (32 cols)
  const int fr = lane & 15;
  const int kq = lane >> 4;            // 0..3
  const int l31 = lane & 31;
  const int rpar = lane >> 5;          // 0/1

  const float* gptr = (wv < 4)
      ? (x + (size_t)(mb * 128 + wv * 32 + rpar) * KIN + l31 * 4)
      : (w + (size_t)((wv - 4) * 32 + rpar) * KIN + l31 * 4);

  f32x4 acc[4][2];
  #pragma unroll
  for (int mi = 0; mi < 4; ++mi) {
    acc[mi][0] = (f32x4){0.f, 0.f, 0.f, 0.f};
    acc[mi][1] = (f32x4){0.f, 0.f, 0.f, 0.f};
  }

  float4 rv[16];
  {
    const float* base = gptr + (size_t)c0 * 128;
    #pragma unroll
    for (int j = 0; j < 16; ++j)
      rv[j] = *(const float4*)(base + (size_t)(j * 2) * KIN);
  }

  for (int cc = 0; cc < nchunk; ++cc) {
    #pragma unroll
    for (int j = 0; j < 16; ++j) {
      const int r = wv * 32 + j * 2 + rpar;
      const int phys = (l31 * 8) ^ ((r & 7) << 4);
      ushort4 bq = {f2bf(rv[j].x), f2bf(rv[j].y), f2bf(rv[j].z), f2bf(rv[j].w)};
      *(ushort4*)(sm + r * 256 + phys) = bq;
    }
    __syncthreads();
    if (cc + 1 < nchunk) {
      const float* base = gptr + (size_t)(c0 + cc + 1) * 128;
      #pragma unroll
      for (int j = 0; j < 16; ++j)
        rv[j] = *(const float4*)(base + (size_t)(j * 2) * KIN);
    }
    #pragma unroll
    for (int ks = 0; ks < 4; ++ks) {
      const int log = ks * 64 + kq * 16;
      bf16x8 a[4];
      #pragma unroll
      for (int mi = 0; mi < 4; ++mi) {
        const int row = wm2 * 64 + mi * 16 + fr;
        a[mi] = *(const bf16x8*)(sm + row * 256 + (log ^ ((row & 7) << 4)));
      }
      #pragma unroll
      for (int ni = 0; ni < 2; ++ni) {
        const int row = 128 + wn4 * 32 + ni * 16 + fr;
        const bf16x8 b = *(const bf16x8*)(sm + row * 256 + (log ^ ((row & 7) << 4)));
        #pragma unroll
        for (int mi = 0; mi < 4; ++mi)
          acc[mi][ni] = __builtin_amdgcn_mfma_f32_16x16x32_bf16(a[mi], b, acc[mi][ni], 0, 0, 0);
      }
    }
    __syncthreads();
  }
  float* hp = partial + (size_t)(kb & 15) * (MTOK * HIDDEN);
  #pragma unroll
  for (int mi = 0; mi < 4; ++mi)
    #pragma unroll
    for (int ni = 0; ni < 2; ++ni)
      #pragma unroll
      for (int r = 0; r < 4; ++r) {
        const int row = mb * 128 + wm2 * 64 + mi * 16 + kq * 4 + r;
        const int col = wn4 * 32 + ni * 16 + fr;
        atomicAdd(hp + (size_t)row * HIDDEN + col, acc[mi][ni][r]);
      }
}

// ---------------------------------------------------------------------------
// fusedA: [out_proj + residual] + rmsnorm + [in_proj next layer]
// mode 0 FIRST (h from part, 16 slices), 1 MID, 2 LAST (final rms -> dout)
// grid 256 (2 tokens/block), block 512.
// y is CHANNEL-MAJOR yT[b][i][t] (single-writer lines in scan_k); read here
// strided from L2 (64 KB/block) -- replaces HBM write amplification.
// ---------------------------------------------------------------------------
__global__ __launch_bounds__(512) void fusedA(
    int mode,
    const float* __restrict__ part, const float* __restrict__ pb,
    const float* __restrict__ yT, const float* __restrict__ gate_g,
    float* __restrict__ h_g,
    const float* __restrict__ opw,   // pre-offset (layer l)
    const float* __restrict__ nw,    // pre-offset norm row (or nwf)
    const float* __restrict__ ipw,   // pre-offset (layer l+1)
    float* __restrict__ hs_g, float* __restrict__ gate_out,
    float* __restrict__ dout)
{
  const int m0 = blockIdx.x * 2;
  const int tid = threadIdx.x;     // 0..511
  const int o2 = tid >> 1;         // 0..255
  const int half = tid & 1;
  const int t = o2 >> 7, d = o2 & 127;
  __shared__ float y2[2][512];
  __shared__ float hrow[2][128];
  __shared__ float hn[2][128];

  float hv;
  if (mode == 0) {
    hv = pb[d];
    #pragma unroll
    for (int s = 0; s < 16; ++s)
      hv += part[(size_t)s * (MTOK * HIDDEN) + (size_t)(m0 + t) * 128 + d];
  } else {
    #pragma unroll
    for (int j = 0; j < 2; ++j) {
      const int o = tid + j * 512;
      const int tt = o >> 9, i = o & 511;
      const int gt = m0 + tt;
      const int b = gt >> 8, tb = gt & 255;
      const float yv = yT[((size_t)b * 512 + i) * 256 + tb];
      const float g  = gate_g[(size_t)gt * 512 + i];
      y2[tt][i] = yv * silu_f(g);
    }
    __syncthreads();
    // out_proj: 2 threads per (t,d), k split 256+256
    const float4* yp = (const float4*)(&y2[t][0] + half * 256);
    const float4* wp = (const float4*)(opw + (size_t)d * 512 + half * 256);
    float a0 = 0.f, a1 = 0.f, a2 = 0.f, a3 = 0.f;
    #pragma unroll 8
    for (int kk = 0; kk < 64; ++kk) {
      const float4 yv = yp[kk], wv4 = wp[kk];
      a0 += yv.x * wv4.x; a1 += yv.y * wv4.y;
      a2 += yv.z * wv4.z; a3 += yv.w * wv4.w;
    }
    float a = (a0 + a1) + (a2 + a3);
    a += __shfl_xor(a, 1);          // both halves hold full dot
    hv = h_g[(size_t)(m0 + t) * 128 + d] + a;
  }
  if (mode != 2 && half == 0) h_g[(size_t)(m0 + t) * 128 + d] = hv;
  if (half == 0) hrow[t][d] = hv;
  __syncthreads();
  // rmsnorm (waves 0..3 replicate tokens 0/1; waves 0,1 write)
  {
    const int wvi = tid >> 6, ln = tid & 63;
    const int tt = wvi & 1;
    const float v0 = hrow[tt][ln], v1 = hrow[tt][ln + 64];
    float ss = v0 * v0 + v1 * v1;
    #pragma unroll
    for (int off = 1; off < 64; off <<= 1) ss += __shfl_xor(ss, off);
    const float rr = rsqrtf(ss * (1.0f / 128.0f) + EPS_RMS);
    if (mode == 2) {
      if (wvi < 2) {
        dout[(size_t)(m0 + tt) * 128 + ln]      = v0 * rr * nw[ln];
        dout[(size_t)(m0 + tt) * 128 + ln + 64] = v1 * rr * nw[ln + 64];
      }
      return;
    }
    if (wvi < 2) {
      hn[tt][ln]      = v0 * rr * nw[ln];
      hn[tt][ln + 64] = v1 * rr * nw[ln + 64];
    }
  }
  __syncthreads();
  // in_proj: 2048 outputs, 4 per thread, k=128 from LDS
  #pragma unroll
  for (int j = 0; j < 4; ++j) {
    const int o = tid + j * 512;
    const int tt = o >> 10, e = o & 1023;
    const float4* hp4 = (const float4*)&hn[tt][0];
    const float4* wp4 = (const float4*)(ipw + (size_t)e * 128);
    float a0 = 0.f, a1 = 0.f, a2 = 0.f, a3 = 0.f;
    #pragma unroll
    for (int kk = 0; kk < 32; ++kk) {
      const float4 hvv = hp4[kk], wv4 = wp4[kk];
      a0 += hvv.x * wv4.x; a1 += hvv.y * wv4.y;
      a2 += hvv.z * wv4.z; a3 += hvv.w * wv4.w;
    }
    const float a = (a0 + a1) + (a2 + a3);
    if (e < 512) hs_g[(size_t)(m0 + tt) * 512 + e] = a;
    else         gate_out[(size_t)(m0 + tt) * 512 + (e - 512)] = a;
  }
}

// ---------------------------------------------------------------------------
// convxp: causal conv(k=4)+silu -> uG ; x_proj -> B,C ; dt softplus -> dtG
// grid 256 (2 tokens/block), block 512. hs halo staged in LDS.
// uG/dtG are TOKEN-MAJOR [b][t][i]: writes fully coalesced, single-writer
// lines (fixes the 16x write amplification measured as 51 MB WRITE_SIZE).
// ---------------------------------------------------------------------------
__global__ __launch_bounds__(512) void convxp(
    const float* __restrict__ hs_g, const float* __restrict__ cw,
    const float* __restrict__ cb, const float* __restrict__ xpw,
    const float* __restrict__ dtw, const float* __restrict__ dtb,
    float* __restrict__ uG, float* __restrict__ dtG,
    float* __restrict__ Bm, float* __restrict__ Cm)
{
  const int m0 = blockIdx.x * 2;
  const int b = m0 >> 8, tb0 = m0 & 255;
  const int tid = threadIdx.x;
  __shared__ float hs5[5][512];
  __shared__ float u4[2][512];
  __shared__ float si[2][40];
  for (int o = tid; o < 2560; o += 512) {        // hs rows tb0-3 .. tb0+1
    const int j = o >> 9, i = o & 511;
    const int ct = tb0 - 3 + j;
    hs5[j][i] = (ct >= 0) ? hs_g[((size_t)b * 256 + ct) * 512 + i] : 0.f;
  }
  __syncthreads();
  #pragma unroll
  for (int j = 0; j < 2; ++j) {                  // conv + silu -> u
    const int o = tid + j * 512;
    const int t = o >> 9, i = o & 511;
    const float4 c4v = *(const float4*)(cw + (size_t)i * 4);
    const float s = cb[i] + c4v.x * hs5[t][i] + c4v.y * hs5[t + 1][i]
                          + c4v.z * hs5[t + 2][i] + c4v.w * hs5[t + 3][i];
    const float uu = silu_f(s);
    u4[t][i] = uu;
    uG[((size_t)b * 256 + tb0 + t) * 512 + i] = uu;   // coalesced
  }
  __syncthreads();
  if (tid < 160) {                               // x_proj: 2 threads/output
    const int pid = tid >> 1, half = tid & 1;
    const int t = pid / 40, e = pid % 40;
    const float4* up = (const float4*)(&u4[t][0] + half * 256);
    const float4* wp = (const float4*)(xpw + (size_t)e * 512 + half * 256);
    float a0 = 0.f, a1 = 0.f, a2 = 0.f, a3 = 0.f;
    #pragma unroll 8
    for (int kk = 0; kk < 64; ++kk) {
      const float4 uv = up[kk], wv4 = wp[kk];
      a0 += uv.x * wv4.x; a1 += uv.y * wv4.y;
      a2 += uv.z * wv4.z; a3 += uv.w * wv4.w;
    }
    float a = (a0 + a1) + (a2 + a3);
    a += __shfl_xor(a, 1);
    if (half == 0) si[t][e] = a;
  }
  __syncthreads();
  if (tid < 64) {                                // B, C rows
    const int t = tid >> 5, q = tid & 31;
    if (q < 16) Bm[(size_t)(m0 + t) * 16 + q] = si[t][8 + q];
    else        Cm[(size_t)(m0 + t) * 16 + (q - 16)] = si[t][24 + (q - 16)];
  }
  #pragma unroll
  for (int j = 0; j < 2; ++j) {                  // dt softplus -> dtG
    const int o = tid + j * 512;
    const int t = o >> 9, i = o & 511;           // token-major: coalesced
    float a0 = dtb[i];
    const float* dr = dtw + (size_t)i * 8;
    #pragma unroll
    for (int r = 0; r < 8; ++r) a0 += si[t][r] * dr[r];
    const float sp = (a0 > 20.f) ? a0 : log1pf(__expf(a0));
    dtG[((size_t)b * 256 + tb0 + t) * 512 + i] = sp;
  }
}

// ---------------------------------------------------------------------------
// scan_k: chunked SSM scan. grid 1024 (one (b,i) per block), block 256
// (16 chunks x 16 states). uG/dtG read strided from L2 (token-major);
// y written CHANNEL-MAJOR yT[b][i][t] -> 1 KB contiguous per block.
// ---------------------------------------------------------------------------
__global__ __launch_bounds__(256) void scan_k(
    const float* __restrict__ uG, const float* __restrict__ dtG,
    const float* __restrict__ Bm, const float* __restrict__ Cm,
    const float* __restrict__ Alog, const float* __restrict__ Dssm,
    float* __restrict__ yT)
{
  const int blk = blockIdx.x;       // 0..1023
  const int b = blk >> 9, i = blk & 511;
  const int tid = threadIdx.x;
  __shared__ float dt_r[256], u_r[256];
  __shared__ float B_l[256][17], C_l[256][17];
  __shared__ float e_l[16][17], P_l[16][17];
  dt_r[tid] = dtG[((size_t)b * 256 + tid) * 512 + i];
  u_r[tid]  = uG [((size_t)b * 256 + tid) * 512 + i];
  #pragma unroll
  for (int j = 0; j < 16; ++j) {
    const int o = tid + j * 256;
    B_l[o >> 4][o & 15] = Bm[(size_t)b * 4096 + o];
    C_l[o >> 4][o & 15] = Cm[(size_t)b * 4096 + o];
  }
  __syncthreads();
  const int c = tid >> 4, n = tid & 15;
  const float Av = -__expf(Alog[(size_t)i * 16 + n]);
  const float Dv = Dssm[i];
  float aj[16], xj[16];
  float s = 0.f, P = 1.f;
  #pragma unroll
  for (int j = 0; j < 16; ++j) {    // pass 1: local scan from 0
    const int t = c * 16 + j;
    const float dtv = dt_r[t];
    const float a = __expf(Av * dtv);
    const float xx = dtv * B_l[t][n] * u_r[t];
    aj[j] = a; xj[j] = xx;
    s = a * s + xx; P *= a;
  }
  e_l[c][n] = s; P_l[c][n] = P;
  __syncthreads();
  float s0 = 0.f;                   // stitch chunk prefixes
  for (int cc = 0; cc < c; ++cc)
    s0 = P_l[cc][n] * s0 + e_l[cc][n];
  s = s0;
  #pragma unroll
  for (int j = 0; j < 16; ++j) {    // pass 2: replay with true state
    const int t = c * 16 + j;
    s = aj[j] * s + xj[j];
    float p = s * C_l[t][n];
    p += __shfl_xor(p, 1); p += __shfl_xor(p, 2);
    p += __shfl_xor(p, 4); p += __shfl_xor(p, 8);
    if (n == 0)
      yT[((size_t)b * 512 + i) * 256 + t] = p + u_r[t] * Dv;  // coalesced
  }
}

extern "C" void kernel_launch(void* const* d_in, const int* in_sizes, int n_in,
                              void* d_out, int out_size, void* d_ws, size_t ws_size,
                              hipStream_t stream)
{
  (void)in_sizes; (void)n_in; (void)out_size; (void)ws_size;
  const float* x    = (const float*)d_in[0];
  const float* pw   = (const float*)d_in[1];
  const float* pb   = (const float*)d_in[2];
  const float* ipw  = (const float*)d_in[3];
  const float* cw   = (const float*)d_in[4];
  const float* cb   = (const float*)d_in[5];
  const float* xpw  = (const float*)d_in[6];
  const float* dtw  = (const float*)d_in[7];
  const float* dtb  = (const float*)d_in[8];
  const float* Alog = (const float*)d_in[9];
  const float* Dssm = (const float*)d_in[10];
  const float* opw  = (const float*)d_in[11];
  const float* nw   = (const float*)d_in[12];
  const float* nwf  = (const float*)d_in[13];
  float* out = (float*)d_out;

  float* ws   = (float*)d_ws;                 // ~10 MB scratch
  float* part = ws;                           // 16 * 65536 (atomic-accumulated)
  float* h    = part + 16 * 65536;            // 65536
  float* hs   = h + 65536;                    // 262144
  float* gate = hs + 262144;                  // 262144
  float* uG   = gate + 262144;                // 262144 (token-major)
  float* dtG  = uG + 262144;                  // 262144 (token-major)
  float* Bm   = dtG + 262144;                 // 8192
  float* Cm   = Bm + 8192;                    // 8192
  float* yT   = Cm + 8192;                    // 262144 (channel-major)

  zero_part<<<dim3(1024), 256, 0, stream>>>(part);
  proj_gemm<<<dim3(256), 512, 0, stream>>>(x, pw, part);

  // first: h from part + rms + in_proj(l=0)
  fusedA<<<dim3(256), 512, 0, stream>>>(0, part, pb, nullptr, nullptr, h,
                                        nullptr, nw, ipw, hs, gate, nullptr);
  for (int l = 0; l < DEPTH; ++l) {
    convxp<<<dim3(256), 512, 0, stream>>>(
        hs, cw + (size_t)l * 2048, cb + (size_t)l * 512,
        xpw + (size_t)l * 40 * 512, dtw + (size_t)l * 512 * 8,
        dtb + (size_t)l * 512, uG, dtG, Bm, Cm);
    scan_k<<<dim3(1024), 256, 0, stream>>>(
        uG, dtG, Bm, Cm, Alog + (size_t)l * 512 * 16, Dssm + (size_t)l * 512, yT);
    if (l < DEPTH - 1)
      fusedA<<<dim3(256), 512, 0, stream>>>(1, nullptr, nullptr, yT, gate, h,
          opw + (size_t)l * 128 * 512, nw + (size_t)(l + 1) * 128,
          ipw + (size_t)(l + 1) * 1024 * 128, hs, gate, nullptr);
    else
      fusedA<<<dim3(256), 512, 0, stream>>>(2, nullptr, nullptr, yT, gate, h,
          opw + (size_t)l * 128 * 512, nwf, nullptr, nullptr, nullptr, out);
  }
}